// Round 1
// 99.005 us; speedup vs baseline: 1.0515x; 1.0515x over previous
//
#include <hip/hip_runtime.h>

#define BB 2
#define LL 1024
#define DD 1024
#define HH 16
#define NC 16
#define EPSF 1e-8f

typedef __attribute__((ext_vector_type(8))) short bf16x8;
typedef __attribute__((ext_vector_type(4))) float f32x4;
typedef unsigned short u16;

static __device__ inline u16 f2bf(float f) {
    unsigned int u = __builtin_bit_cast(unsigned int, f);
    u += 0x7fff + ((u >> 16) & 1);     // RNE
    return (u16)(u >> 16);
}
static __device__ inline float bf2f(u16 v) {
    unsigned int u = ((unsigned int)v) << 16;
    return __builtin_bit_cast(float, u);
}
static __device__ inline void gload_lds16(const u16* g, u16* l) {
    __builtin_amdgcn_global_load_lds((const __attribute__((address_space(1))) void*)g,
                                     (__attribute__((address_space(3))) void*)l, 16, 0, 0);
}

// ---------------- fp32 -> bf16 convert: X (2M), Wq (1M), Wv (1M)
__global__ __launch_bounds__(256) void cvt_k(const float* __restrict__ X,
                                             const float* __restrict__ Wq,
                                             const float* __restrict__ Wv,
                                             u16* __restrict__ Xb,
                                             u16* __restrict__ Wqb,
                                             u16* __restrict__ Wvb)
{
    int i = (blockIdx.x * 256 + threadIdx.x) * 4;
    const float* s; u16* d; int off;
    if (i < 2*1024*1024)      { s = X;  d = Xb;  off = i; }
    else if (i < 3*1024*1024) { s = Wq; d = Wqb; off = i - 2*1024*1024; }
    else                      { s = Wv; d = Wvb; off = i - 3*1024*1024; }
    float4 v = *(const float4*)(s + off);
    ushort4 o;
    o.x = f2bf(v.x); o.y = f2bf(v.y); o.z = f2bf(v.z); o.w = f2bf(v.w);
    *(ushort4*)(d + off) = o;
}

// ---------------- bf16 MFMA GEMM + fused per-head RMSNorm, bf16 out.
// 128(M) x 64(N) tile, BK=64 via two ping LDS slices; 512 blocks (2/CU).
// z=1 (V path) additionally computes the per-chunk S_c^T = V_c^T K_c tiles
// in its epilogue (fused former kv_chunk kernel).
// LDS chunk swizzle: slot = chunk ^ ((row>>1)&3) applied on BOTH the
// global_load_lds per-lane SOURCE and the ds_read (rule #21) to break the
// 8-way bank conflict of the 64B-stride rows.
__global__ __launch_bounds__(256) void gemm_fused(const u16* __restrict__ Xb,
                                                  const u16* __restrict__ Wqb,
                                                  const u16* __restrict__ Wvb,
                                                  const float* __restrict__ qw,
                                                  const float* __restrict__ vw,
                                                  u16* __restrict__ Qb,
                                                  u16* __restrict__ Vb,
                                                  u16* __restrict__ S)
{
    const int K = DD, N = DD;
    const u16* W = blockIdx.z ? Wvb : Wqb;
    const float* nw = blockIdx.z ? vw : qw;
    u16* Y = blockIdx.z ? Vb : Qb;
    __shared__ u16 As0[128 * 32], As1[128 * 32];
    __shared__ u16 Bs0[64 * 32],  Bs1[64 * 32];
    __shared__ u16 Vt[64][136];   // [e][l] normalized V, both chunks (z=1 only)
    __shared__ u16 Kt[64][136];   // [d][l] K tile, both chunks (z=1 only)

    const int tid = threadIdx.x, w = tid >> 6, lane = tid & 63;
    const int quad = lane >> 4, l16 = lane & 15;
    const int m0 = blockIdx.y * 128, n0 = blockIdx.x * 64;
    const int lrow = lane >> 2;
    const int lcol = ((lane & 3) ^ ((lane >> 3) & 3)) * 8;   // swizzled source chunk

    const u16* gA0 = Xb + (size_t)(m0 + w*16 + lrow) * K + lcol;
    const u16* gA1 = gA0 + (size_t)64 * K;
    const u16* gB0 = W + (size_t)(n0 + w*16 + lrow) * K + lcol;
    u16* lA0_0 = &As0[(w*16) * 32];      u16* lA0_1 = &As1[(w*16) * 32];
    u16* lA1_0 = &As0[(64 + w*16) * 32]; u16* lA1_1 = &As1[(64 + w*16) * 32];
    u16* lB0_0 = &Bs0[(w*16) * 32];      u16* lB0_1 = &Bs1[(w*16) * 32];

    const int sw = (quad ^ ((l16 >> 1) & 3)) * 8;            // swizzled read slot

    f32x4 acc[2][4] = {};
    for (int k0 = 0; k0 < K; k0 += 64) {
        gload_lds16(gA0 + k0,      lA0_0);
        gload_lds16(gA0 + k0 + 32, lA0_1);
        gload_lds16(gA1 + k0,      lA1_0);
        gload_lds16(gA1 + k0 + 32, lA1_1);
        gload_lds16(gB0 + k0,      lB0_0);
        gload_lds16(gB0 + k0 + 32, lB0_1);
        __syncthreads();
        #pragma unroll
        for (int hh = 0; hh < 2; ++hh) {
            const u16* Ah = hh ? As1 : As0;
            const u16* Bh = hh ? Bs1 : Bs0;
            bf16x8 af[2], bfr[4];
            #pragma unroll
            for (int i = 0; i < 2; ++i)
                af[i] = *(const bf16x8*)&Ah[(w*32 + i*16 + l16) * 32 + sw];
            #pragma unroll
            for (int j = 0; j < 4; ++j)
                bfr[j] = *(const bf16x8*)&Bh[(j*16 + l16) * 32 + sw];
            #pragma unroll
            for (int i = 0; i < 2; ++i)
                #pragma unroll
                for (int j = 0; j < 4; ++j)
                    acc[i][j] = __builtin_amdgcn_mfma_f32_16x16x32_bf16(af[i], bfr[j], acc[i][j], 0, 0, 0);
        }
        __syncthreads();
    }

    float wv4[4];
    #pragma unroll
    for (int j = 0; j < 4; ++j) wv4[j] = nw[n0 + j*16 + l16];
    #pragma unroll
    for (int i = 0; i < 2; ++i) {
        float ss[4];
        #pragma unroll
        for (int r = 0; r < 4; ++r) {
            float s = 0.f;
            #pragma unroll
            for (int j = 0; j < 4; ++j) s += acc[i][j][r] * acc[i][j][r];
            ss[r] = s;
        }
        #pragma unroll
        for (int off = 1; off < 16; off <<= 1)
            #pragma unroll
            for (int r = 0; r < 4; ++r) ss[r] += __shfl_xor(ss[r], off, 64);
        float sc[4];
        #pragma unroll
        for (int r = 0; r < 4; ++r) sc[r] = rsqrtf(ss[r] * (1.f/64.f) + EPSF);
        #pragma unroll
        for (int r = 0; r < 4; ++r) {
            u16* yp = Y + (size_t)(m0 + w*32 + i*16 + quad*4 + r) * N + n0;
            #pragma unroll
            for (int j = 0; j < 4; ++j) {
                u16 val = f2bf(acc[i][j][r] * sc[r] * wv4[j]);
                yp[j*16 + l16] = val;
                if (blockIdx.z)
                    Vt[j*16 + l16][w*32 + i*16 + quad*4 + r] = val;
            }
        }
    }

    // ---------- fused per-chunk S epilogue (V path only) ----------
    if (blockIdx.z) {
        {   // stage K tile (Xb rows m0..m0+127, this head's 64 cols), transposed
            const int row = tid >> 1, q2 = tid & 1;
            size_t gb = (size_t)(m0 + row) * DD + n0 + q2 * 32;
            u16 kk[32];
            #pragma unroll
            for (int i2 = 0; i2 < 32; i2 += 4)
                *(ushort4*)&kk[i2] = *(const ushort4*)(Xb + gb + i2);
            #pragma unroll
            for (int i2 = 0; i2 < 32; ++i2)
                Kt[q2*32 + i2][row] = kk[i2];
        }
        __syncthreads();
        const int me = (w & 1) * 32, nd = (w >> 1) * 32;
        const int b = m0 >> 10, c0 = (m0 & 1023) >> 6, h = blockIdx.x;
        const int bh = b * HH + h;
        #pragma unroll
        for (int cc = 0; cc < 2; ++cc) {
            f32x4 sacc[2][2] = {};
            #pragma unroll
            for (int k0 = 0; k0 < 64; k0 += 32) {
                bf16x8 av[2], bv[2];
                #pragma unroll
                for (int i2 = 0; i2 < 2; ++i2)
                    av[i2] = *(const bf16x8*)&Vt[me + i2*16 + l16][cc*64 + k0 + quad*8];
                #pragma unroll
                for (int j2 = 0; j2 < 2; ++j2)
                    bv[j2] = *(const bf16x8*)&Kt[nd + j2*16 + l16][cc*64 + k0 + quad*8];
                #pragma unroll
                for (int i2 = 0; i2 < 2; ++i2)
                    #pragma unroll
                    for (int j2 = 0; j2 < 2; ++j2)
                        sacc[i2][j2] = __builtin_amdgcn_mfma_f32_16x16x32_bf16(av[i2], bv[j2], sacc[i2][j2], 0, 0, 0);
            }
            // same flat C-layout + tile indexing as the former kv_chunk kernel
            u16* Sp = S + ((size_t)((bh << 4) | (c0 + cc)) << 12) + w*1024;
            #pragma unroll
            for (int i2 = 0; i2 < 2; ++i2)
                #pragma unroll
                for (int j2 = 0; j2 < 2; ++j2)
                    #pragma unroll
                    for (int r = 0; r < 4; ++r)
                        Sp[(i2*2 + j2)*256 + r*64 + lane] = f2bf(sacc[i2][j2][r]);
        }
    }
}

// ---------------- out = tril(Q K^T) @ V + Q @ S0; block sums its own prefix
// from the parallel per-chunk S tiles (L2-resident, avg 7.5 x 8 KB).
__global__ __launch_bounds__(256) void out_k2(const u16* __restrict__ Xb,
                                              const u16* __restrict__ Qb,
                                              const u16* __restrict__ Vb,
                                              const u16* __restrict__ S,
                                              float* __restrict__ out)
{
    const int c = 15 - (blockIdx.x & 15);   // heavy (large-c) blocks first
    const int bh = blockIdx.x >> 4;
    const int h = bh & 15, b = bh >> 4;
    __shared__ u16 Qs[64][72];   // [l][d]
    __shared__ u16 Ks[64][72];   // [l'][d] -> later Ps [l][l']
    __shared__ u16 Vt[64][72];   // [e][l']
    __shared__ u16 St[64][72];   // [e][d]  summed prefix, bf16
    const int tid = threadIdx.x;
    {
        const int row = tid >> 2, q = tid & 3;
        size_t gbase = (size_t)(b*LL + c*64 + row) * DD + h*64 + q*16;
        u16 vv[16];
        #pragma unroll
        for (int i = 0; i < 16; i += 4) {
            *(ushort4*)&Qs[row][q*16 + i] = *(const ushort4*)(Qb + gbase + i);
            *(ushort4*)&Ks[row][q*16 + i] = *(const ushort4*)(Xb + gbase + i);
            *(ushort4*)&vv[i] = *(const ushort4*)(Vb + gbase + i);
        }
        #pragma unroll
        for (int i = 0; i < 16; ++i)
            Vt[q*16 + i][row] = vv[i];
        // prefix sum of earlier chunk tiles: 16 fp32 accumulators per thread.
        // unrolled x2 for load ILP (accumulation order preserved).
        float facc[16] = {};
        const u16* Sbase = S + ((size_t)(bh * NC) << 12);
        int cp = 0;
        for (; cp + 2 <= c; cp += 2) {
            const u16* Sc0 = Sbase + ((size_t)cp << 12);
            const u16* Sc1 = Sc0 + 4096;
            #pragma unroll
            for (int jj = 0; jj < 4; ++jj) {
                ushort4 sv0 = *(const ushort4*)(Sc0 + tid*4 + jj*1024);
                ushort4 sv1 = *(const ushort4*)(Sc1 + tid*4 + jj*1024);
                facc[jj*4+0] += bf2f(sv0.x); facc[jj*4+0] += bf2f(sv1.x);
                facc[jj*4+1] += bf2f(sv0.y); facc[jj*4+1] += bf2f(sv1.y);
                facc[jj*4+2] += bf2f(sv0.z); facc[jj*4+2] += bf2f(sv1.z);
                facc[jj*4+3] += bf2f(sv0.w); facc[jj*4+3] += bf2f(sv1.w);
            }
        }
        if (cp < c) {
            const u16* Sc = Sbase + ((size_t)cp << 12);
            #pragma unroll
            for (int jj = 0; jj < 4; ++jj) {
                ushort4 sv = *(const ushort4*)(Sc + tid*4 + jj*1024);
                facc[jj*4+0] += bf2f(sv.x);
                facc[jj*4+1] += bf2f(sv.y);
                facc[jj*4+2] += bf2f(sv.z);
                facc[jj*4+3] += bf2f(sv.w);
            }
        }
        // decode flat C-layout and write St[e][d..d+3]
        #pragma unroll
        for (int jj = 0; jj < 4; ++jj) {
            int g = tid * 4;                 // offset within the 1024-elem quadrant
            int ij = (g >> 8) & 3, r = (g >> 6) & 3, ln = g & 63;
            int e = (jj & 1)*32 + (ij >> 1)*16 + (ln >> 4)*4 + r;
            int d = (jj >> 1)*32 + (ij & 1)*16 + (ln & 15);
            ushort4 o;
            o.x = f2bf(facc[jj*4+0]);
            o.y = f2bf(facc[jj*4+1]);
            o.z = f2bf(facc[jj*4+2]);
            o.w = f2bf(facc[jj*4+3]);
            *(ushort4*)&St[e][d] = o;
        }
    }
    __syncthreads();
    const int w = tid >> 6, lane = tid & 63, quad = lane >> 4, l16 = lane & 15;
    const int mo = (w & 1) * 32, no = (w >> 1) * 32;

    // P = Q K^T, causal-masked, bf16 (Ps aliases Ks)
    f32x4 pacc[2][2] = {};
    #pragma unroll
    for (int k0 = 0; k0 < 64; k0 += 32) {
        bf16x8 aq[2], bk[2];
        #pragma unroll
        for (int i = 0; i < 2; ++i)
            aq[i] = *(const bf16x8*)&Qs[mo + i*16 + l16][k0 + quad*8];
        #pragma unroll
        for (int j = 0; j < 2; ++j)
            bk[j] = *(const bf16x8*)&Ks[no + j*16 + l16][k0 + quad*8];
        #pragma unroll
        for (int i = 0; i < 2; ++i)
            #pragma unroll
            for (int j = 0; j < 2; ++j)
                pacc[i][j] = __builtin_amdgcn_mfma_f32_16x16x32_bf16(aq[i], bk[j], pacc[i][j], 0, 0, 0);
    }
    __syncthreads();
    #pragma unroll
    for (int i = 0; i < 2; ++i)
        #pragma unroll
        for (int j = 0; j < 2; ++j)
            #pragma unroll
            for (int r = 0; r < 4; ++r) {
                int l  = mo + i*16 + quad*4 + r;
                int lp = no + j*16 + l16;
                Ks[l][lp] = (lp <= l) ? f2bf(pacc[i][j][r]) : (u16)0;
            }
    __syncthreads();

    // O = P @ V + Q @ S0
    f32x4 acc[2][2] = {};
    #pragma unroll
    for (int k0 = 0; k0 < 64; k0 += 32) {
        bf16x8 a1[2], b1[2], a2[2], b2[2];
        #pragma unroll
        for (int i = 0; i < 2; ++i) {
            a1[i] = *(const bf16x8*)&Ks[mo + i*16 + l16][k0 + quad*8];
            a2[i] = *(const bf16x8*)&Qs[mo + i*16 + l16][k0 + quad*8];
        }
        #pragma unroll
        for (int j = 0; j < 2; ++j) {
            b1[j] = *(const bf16x8*)&Vt[no + j*16 + l16][k0 + quad*8];
            b2[j] = *(const bf16x8*)&St[no + j*16 + l16][k0 + quad*8];
        }
        #pragma unroll
        for (int i = 0; i < 2; ++i)
            #pragma unroll
            for (int j = 0; j < 2; ++j) {
                acc[i][j] = __builtin_amdgcn_mfma_f32_16x16x32_bf16(a1[i], b1[j], acc[i][j], 0, 0, 0);
                acc[i][j] = __builtin_amdgcn_mfma_f32_16x16x32_bf16(a2[i], b2[j], acc[i][j], 0, 0, 0);
            }
    }
    float* op = out + (size_t)(b*LL + c*64) * DD + h*64;
    #pragma unroll
    for (int i = 0; i < 2; ++i)
        #pragma unroll
        for (int j = 0; j < 2; ++j)
            #pragma unroll
            for (int r = 0; r < 4; ++r)
                op[(size_t)(mo + i*16 + quad*4 + r) * DD + no + j*16 + l16] = acc[i][j][r];
}

extern "C" void kernel_launch(void* const* d_in, const int* in_sizes, int n_in,
                              void* d_out, int out_size, void* d_ws, size_t ws_size,
                              hipStream_t stream) {
    const float* X  = (const float*)d_in[0];
    const float* Wq = (const float*)d_in[1];
    const float* Wv = (const float*)d_in[2];
    const float* qw = (const float*)d_in[3];
    const float* vw = (const float*)d_in[4];
    float* out = (float*)d_out;

    u16* Xb  = (u16*)d_ws;                        // 2M u16
    u16* Wqb = Xb  + (size_t)2*1024*1024;         // 1M
    u16* Wvb = Wqb + (size_t)1024*1024;           // 1M
    u16* Qb  = Wvb + (size_t)1024*1024;           // 2M
    u16* Vb  = Qb  + (size_t)2*1024*1024;         // 2M
    u16* S   = Vb  + (size_t)2*1024*1024;         // 2M u16

    cvt_k<<<4096, 256, 0, stream>>>(X, Wq, Wv, Xb, Wqb, Wvb);
    gemm_fused<<<dim3(16, 16, 2), 256, 0, stream>>>(Xb, Wqb, Wvb, qw, vw, Qb, Vb, S);
    out_k2<<<BB*HH*NC, 256, 0, stream>>>(Xb, Qb, Vb, S, out);
}

// Round 2
// 96.960 us; speedup vs baseline: 1.0737x; 1.0211x over previous
//
#include <hip/hip_runtime.h>

#define BB 2
#define LL 1024
#define DD 1024
#define HH 16
#define NC 16
#define EPSF 1e-8f

typedef __attribute__((ext_vector_type(8))) short bf16x8;
typedef __attribute__((ext_vector_type(4))) float f32x4;
typedef unsigned short u16;

static __device__ inline u16 f2bf(float f) {
    unsigned int u = __builtin_bit_cast(unsigned int, f);
    u += 0x7fff + ((u >> 16) & 1);     // RNE
    return (u16)(u >> 16);
}
static __device__ inline float bf2f(u16 v) {
    unsigned int u = ((unsigned int)v) << 16;
    return __builtin_bit_cast(float, u);
}
static __device__ inline void gload_lds16(const u16* g, u16* l) {
    __builtin_amdgcn_global_load_lds((const __attribute__((address_space(1))) void*)g,
                                     (__attribute__((address_space(3))) void*)l, 16, 0, 0);
}

// ---------------- fp32 -> bf16 convert: X (2M), Wq (1M), Wv (1M)
__global__ __launch_bounds__(256) void cvt_k(const float* __restrict__ X,
                                             const float* __restrict__ Wq,
                                             const float* __restrict__ Wv,
                                             u16* __restrict__ Xb,
                                             u16* __restrict__ Wqb,
                                             u16* __restrict__ Wvb)
{
    int i = (blockIdx.x * 256 + threadIdx.x) * 4;
    const float* s; u16* d; int off;
    if (i < 2*1024*1024)      { s = X;  d = Xb;  off = i; }
    else if (i < 3*1024*1024) { s = Wq; d = Wqb; off = i - 2*1024*1024; }
    else                      { s = Wv; d = Wvb; off = i - 3*1024*1024; }
    float4 v = *(const float4*)(s + off);
    ushort4 o;
    o.x = f2bf(v.x); o.y = f2bf(v.y); o.z = f2bf(v.z); o.w = f2bf(v.w);
    *(ushort4*)(d + off) = o;
}

// ---------------- bf16 MFMA GEMM + fused per-head RMSNorm, bf16 out.
// 128(M) x 64(N) tile, BK=64, DOUBLE-BUFFERED (stage k+1 || compute k,
// one barrier per K-step = T3 minimum 2-phase). LDS layout: [row][64]
// unified rows (128 B); XOR chunk swizzle (lane&7)^(row&7) applied on
// BOTH the per-lane global source and the ds_read (rule #21) -> only
// free 2-way bank aliasing on the MFMA fragment reads.
// Epilogue Vt/Kt (V path S-tiles) UNION the A/B buffers (48 KB total).
__global__ __launch_bounds__(256) void gemm_fused(const u16* __restrict__ Xb,
                                                  const u16* __restrict__ Wqb,
                                                  const u16* __restrict__ Wvb,
                                                  const float* __restrict__ qw,
                                                  const float* __restrict__ vw,
                                                  u16* __restrict__ Qb,
                                                  u16* __restrict__ Vb,
                                                  u16* __restrict__ S)
{
    const int K = DD, N = DD;
    const u16* W = blockIdx.z ? Wvb : Wqb;
    const float* nw = blockIdx.z ? vw : qw;
    u16* Y = blockIdx.z ? Vb : Qb;

    __shared__ alignas(16) char smem[49152];
    u16* Ab = (u16*)smem;                 // [2][128*64]  (32768 B)
    u16* Bb = (u16*)(smem + 32768);       // [2][64*64]   (16384 B)

    const int tid = threadIdx.x, w = tid >> 6, lane = tid & 63;
    const int quad = lane >> 4, l16 = lane & 15;
    const int m0 = blockIdx.y * 128, n0 = blockIdx.x * 64;

    // staging: per gload call, lane -> row (lane>>3), phys chunk (lane&7).
    // source logical chunk = (lane&7) ^ (row&7) = (lane&7) ^ (lane>>3).
    const int lr8 = lane >> 3;
    const int lc8 = (lane & 7) ^ lr8;
    const u16* gA = Xb + (size_t)(m0 + w*32 + lr8) * K + lc8 * 8;
    const u16* gB = W  + (size_t)(n0 + w*16 + lr8) * K + lc8 * 8;

    f32x4 acc[2][4] = {};

    auto stage = [&](int buf, int k0) {
        u16* As = Ab + buf * (128*64);
        u16* Bs = Bb + buf * (64*64);
        #pragma unroll
        for (int q = 0; q < 4; ++q)
            gload_lds16(gA + k0 + (size_t)q*8*K, As + (w*32 + q*8)*64);
        #pragma unroll
        for (int q = 0; q < 2; ++q)
            gload_lds16(gB + k0 + (size_t)q*8*K, Bs + (w*16 + q*8)*64);
    };
    auto compute = [&](int buf) {
        const u16* As = Ab + buf * (128*64);
        const u16* Bs = Bb + buf * (64*64);
        #pragma unroll
        for (int hh = 0; hh < 2; ++hh) {
            const int co = (((hh << 2) | quad) ^ (l16 & 7)) * 8;
            bf16x8 af[2], bfr[4];
            #pragma unroll
            for (int i = 0; i < 2; ++i)
                af[i] = *(const bf16x8*)&As[(w*32 + i*16 + l16) * 64 + co];
            #pragma unroll
            for (int j = 0; j < 4; ++j)
                bfr[j] = *(const bf16x8*)&Bs[(j*16 + l16) * 64 + co];
            #pragma unroll
            for (int i = 0; i < 2; ++i)
                #pragma unroll
                for (int j = 0; j < 4; ++j)
                    acc[i][j] = __builtin_amdgcn_mfma_f32_16x16x32_bf16(af[i], bfr[j], acc[i][j], 0, 0, 0);
        }
    };

    stage(0, 0);
    __syncthreads();                 // vmcnt(0) drain + barrier
    int cur = 0;
    for (int k0 = 0; k0 < K; k0 += 64) {
        if (k0 + 64 < K) stage(cur ^ 1, k0 + 64);   // loads fly under compute
        compute(cur);
        __syncthreads();             // drains vmcnt+lgkmcnt, flips buffer
        cur ^= 1;
    }

    // epilogue LDS union (only live after the final barrier above)
    u16 (*Vt)[136] = (u16 (*)[136])smem;            // [64][136]  17408 B
    u16 (*Kt)[136] = (u16 (*)[136])(smem + 17408);  // [64][136]  17408 B

    float wv4[4];
    #pragma unroll
    for (int j = 0; j < 4; ++j) wv4[j] = nw[n0 + j*16 + l16];
    #pragma unroll
    for (int i = 0; i < 2; ++i) {
        float ss[4];
        #pragma unroll
        for (int r = 0; r < 4; ++r) {
            float s = 0.f;
            #pragma unroll
            for (int j = 0; j < 4; ++j) s += acc[i][j][r] * acc[i][j][r];
            ss[r] = s;
        }
        #pragma unroll
        for (int off = 1; off < 16; off <<= 1)
            #pragma unroll
            for (int r = 0; r < 4; ++r) ss[r] += __shfl_xor(ss[r], off, 64);
        float sc[4];
        #pragma unroll
        for (int r = 0; r < 4; ++r) sc[r] = rsqrtf(ss[r] * (1.f/64.f) + EPSF);
        #pragma unroll
        for (int r = 0; r < 4; ++r) {
            u16* yp = Y + (size_t)(m0 + w*32 + i*16 + quad*4 + r) * N + n0;
            #pragma unroll
            for (int j = 0; j < 4; ++j) {
                u16 val = f2bf(acc[i][j][r] * sc[r] * wv4[j]);
                yp[j*16 + l16] = val;
                if (blockIdx.z)
                    Vt[j*16 + l16][w*32 + i*16 + quad*4 + r] = val;
            }
        }
    }

    // ---------- fused per-chunk S epilogue (V path only) ----------
    if (blockIdx.z) {
        {   // stage K tile (Xb rows m0..m0+127, this head's 64 cols), transposed
            const int row = tid >> 1, q2 = tid & 1;
            size_t gb = (size_t)(m0 + row) * DD + n0 + q2 * 32;
            u16 kk[32];
            #pragma unroll
            for (int i2 = 0; i2 < 32; i2 += 4)
                *(ushort4*)&kk[i2] = *(const ushort4*)(Xb + gb + i2);
            #pragma unroll
            for (int i2 = 0; i2 < 32; ++i2)
                Kt[q2*32 + i2][row] = kk[i2];
        }
        __syncthreads();
        const int me = (w & 1) * 32, nd = (w >> 1) * 32;
        const int b = m0 >> 10, c0 = (m0 & 1023) >> 6, h = blockIdx.x;
        const int bh = b * HH + h;
        #pragma unroll
        for (int cc = 0; cc < 2; ++cc) {
            f32x4 sacc[2][2] = {};
            #pragma unroll
            for (int k0 = 0; k0 < 64; k0 += 32) {
                bf16x8 av[2], bv[2];
                #pragma unroll
                for (int i2 = 0; i2 < 2; ++i2)
                    av[i2] = *(const bf16x8*)&Vt[me + i2*16 + l16][cc*64 + k0 + quad*8];
                #pragma unroll
                for (int j2 = 0; j2 < 2; ++j2)
                    bv[j2] = *(const bf16x8*)&Kt[nd + j2*16 + l16][cc*64 + k0 + quad*8];
                #pragma unroll
                for (int i2 = 0; i2 < 2; ++i2)
                    #pragma unroll
                    for (int j2 = 0; j2 < 2; ++j2)
                        sacc[i2][j2] = __builtin_amdgcn_mfma_f32_16x16x32_bf16(av[i2], bv[j2], sacc[i2][j2], 0, 0, 0);
            }
            // same flat C-layout + tile indexing as the former kv_chunk kernel
            u16* Sp = S + ((size_t)((bh << 4) | (c0 + cc)) << 12) + w*1024;
            #pragma unroll
            for (int i2 = 0; i2 < 2; ++i2)
                #pragma unroll
                for (int j2 = 0; j2 < 2; ++j2)
                    #pragma unroll
                    for (int r = 0; r < 4; ++r)
                        Sp[(i2*2 + j2)*256 + r*64 + lane] = f2bf(sacc[i2][j2][r]);
        }
    }
}

// ---------------- out = tril(Q K^T) @ V + Q @ S0; block sums its own prefix
// from the parallel per-chunk S tiles (L2/L3-resident, avg 7.5 x 8 KB).
__global__ __launch_bounds__(256) void out_k2(const u16* __restrict__ Xb,
                                              const u16* __restrict__ Qb,
                                              const u16* __restrict__ Vb,
                                              const u16* __restrict__ S,
                                              float* __restrict__ out)
{
    const int c = 15 - (blockIdx.x & 15);   // heavy (large-c) blocks first
    const int bh = blockIdx.x >> 4;
    const int h = bh & 15, b = bh >> 4;
    __shared__ u16 Qs[64][72];   // [l][d]
    __shared__ u16 Ks[64][72];   // [l'][d] -> later Ps [l][l']
    __shared__ u16 Vt[64][72];   // [e][l']
    __shared__ u16 St[64][72];   // [e][d]  summed prefix, bf16
    const int tid = threadIdx.x;
    {
        const int row = tid >> 2, q = tid & 3;
        size_t gbase = (size_t)(b*LL + c*64 + row) * DD + h*64 + q*16;
        u16 vv[16];
        #pragma unroll
        for (int i = 0; i < 16; i += 4) {
            *(ushort4*)&Qs[row][q*16 + i] = *(const ushort4*)(Qb + gbase + i);
            *(ushort4*)&Ks[row][q*16 + i] = *(const ushort4*)(Xb + gbase + i);
            *(ushort4*)&vv[i] = *(const ushort4*)(Vb + gbase + i);
        }
        #pragma unroll
        for (int i = 0; i < 16; ++i)
            Vt[q*16 + i][row] = vv[i];
        // prefix sum of earlier chunk tiles: 16 fp32 accumulators per thread.
        // unrolled x4 for load ILP (element-wise accumulation order preserved).
        float facc[16] = {};
        const u16* Sbase = S + ((size_t)(bh * NC) << 12);
        int cp = 0;
        for (; cp + 4 <= c; cp += 4) {
            ushort4 sv[4][4];
            #pragma unroll
            for (int u = 0; u < 4; ++u)
                #pragma unroll
                for (int jj = 0; jj < 4; ++jj)
                    sv[u][jj] = *(const ushort4*)(Sbase + ((size_t)(cp + u) << 12) + tid*4 + jj*1024);
            #pragma unroll
            for (int u = 0; u < 4; ++u)
                #pragma unroll
                for (int jj = 0; jj < 4; ++jj) {
                    facc[jj*4+0] += bf2f(sv[u][jj].x);
                    facc[jj*4+1] += bf2f(sv[u][jj].y);
                    facc[jj*4+2] += bf2f(sv[u][jj].z);
                    facc[jj*4+3] += bf2f(sv[u][jj].w);
                }
        }
        for (; cp < c; ++cp) {
            const u16* Sc = Sbase + ((size_t)cp << 12);
            #pragma unroll
            for (int jj = 0; jj < 4; ++jj) {
                ushort4 sv = *(const ushort4*)(Sc + tid*4 + jj*1024);
                facc[jj*4+0] += bf2f(sv.x);
                facc[jj*4+1] += bf2f(sv.y);
                facc[jj*4+2] += bf2f(sv.z);
                facc[jj*4+3] += bf2f(sv.w);
            }
        }
        // decode flat C-layout and write St[e][d..d+3]
        #pragma unroll
        for (int jj = 0; jj < 4; ++jj) {
            int g = tid * 4;                 // offset within the 1024-elem quadrant
            int ij = (g >> 8) & 3, r = (g >> 6) & 3, ln = g & 63;
            int e = (jj & 1)*32 + (ij >> 1)*16 + (ln >> 4)*4 + r;
            int d = (jj >> 1)*32 + (ij & 1)*16 + (ln & 15);
            ushort4 o;
            o.x = f2bf(facc[jj*4+0]);
            o.y = f2bf(facc[jj*4+1]);
            o.z = f2bf(facc[jj*4+2]);
            o.w = f2bf(facc[jj*4+3]);
            *(ushort4*)&St[e][d] = o;
        }
    }
    __syncthreads();
    const int w = tid >> 6, lane = tid & 63, quad = lane >> 4, l16 = lane & 15;
    const int mo = (w & 1) * 32, no = (w >> 1) * 32;

    // P = Q K^T, causal-masked, bf16 (Ps aliases Ks)
    f32x4 pacc[2][2] = {};
    #pragma unroll
    for (int k0 = 0; k0 < 64; k0 += 32) {
        bf16x8 aq[2], bk[2];
        #pragma unroll
        for (int i = 0; i < 2; ++i)
            aq[i] = *(const bf16x8*)&Qs[mo + i*16 + l16][k0 + quad*8];
        #pragma unroll
        for (int j = 0; j < 2; ++j)
            bk[j] = *(const bf16x8*)&Ks[no + j*16 + l16][k0 + quad*8];
        #pragma unroll
        for (int i = 0; i < 2; ++i)
            #pragma unroll
            for (int j = 0; j < 2; ++j)
                pacc[i][j] = __builtin_amdgcn_mfma_f32_16x16x32_bf16(aq[i], bk[j], pacc[i][j], 0, 0, 0);
    }
    __syncthreads();
    #pragma unroll
    for (int i = 0; i < 2; ++i)
        #pragma unroll
        for (int j = 0; j < 2; ++j)
            #pragma unroll
            for (int r = 0; r < 4; ++r) {
                int l  = mo + i*16 + quad*4 + r;
                int lp = no + j*16 + l16;
                Ks[l][lp] = (lp <= l) ? f2bf(pacc[i][j][r]) : (u16)0;
            }
    __syncthreads();

    // O = P @ V + Q @ S0
    f32x4 acc[2][2] = {};
    #pragma unroll
    for (int k0 = 0; k0 < 64; k0 += 32) {
        bf16x8 a1[2], b1[2], a2[2], b2[2];
        #pragma unroll
        for (int i = 0; i < 2; ++i) {
            a1[i] = *(const bf16x8*)&Ks[mo + i*16 + l16][k0 + quad*8];
            a2[i] = *(const bf16x8*)&Qs[mo + i*16 + l16][k0 + quad*8];
        }
        #pragma unroll
        for (int j = 0; j < 2; ++j) {
            b1[j] = *(const bf16x8*)&Vt[no + j*16 + l16][k0 + quad*8];
            b2[j] = *(const bf16x8*)&St[no + j*16 + l16][k0 + quad*8];
        }
        #pragma unroll
        for (int i = 0; i < 2; ++i)
            #pragma unroll
            for (int j = 0; j < 2; ++j) {
                acc[i][j] = __builtin_amdgcn_mfma_f32_16x16x32_bf16(a1[i], b1[j], acc[i][j], 0, 0, 0);
                acc[i][j] = __builtin_amdgcn_mfma_f32_16x16x32_bf16(a2[i], b2[j], acc[i][j], 0, 0, 0);
            }
    }
    float* op = out + (size_t)(b*LL + c*64) * DD + h*64;
    #pragma unroll
    for (int i = 0; i < 2; ++i)
        #pragma unroll
        for (int j = 0; j < 2; ++j)
            #pragma unroll
            for (int r = 0; r < 4; ++r)
                op[(size_t)(mo + i*16 + quad*4 + r) * DD + no + j*16 + l16] = acc[i][j][r];
}

extern "C" void kernel_launch(void* const* d_in, const int* in_sizes, int n_in,
                              void* d_out, int out_size, void* d_ws, size_t ws_size,
                              hipStream_t stream) {
    const float* X  = (const float*)d_in[0];
    const float* Wq = (const float*)d_in[1];
    const float* Wv = (const float*)d_in[2];
    const float* qw = (const float*)d_in[3];
    const float* vw = (const float*)d_in[4];
    float* out = (float*)d_out;

    u16* Xb  = (u16*)d_ws;                        // 2M u16
    u16* Wqb = Xb  + (size_t)2*1024*1024;         // 1M
    u16* Wvb = Wqb + (size_t)1024*1024;           // 1M
    u16* Qb  = Wvb + (size_t)1024*1024;           // 2M
    u16* Vb  = Qb  + (size_t)2*1024*1024;         // 2M
    u16* S   = Vb  + (size_t)2*1024*1024;         // 2M u16

    cvt_k<<<4096, 256, 0, stream>>>(X, Wq, Wv, Xb, Wqb, Wvb);
    gemm_fused<<<dim3(16, 16, 2), 256, 0, stream>>>(Xb, Wqb, Wvb, qw, vw, Qb, Vb, S);
    out_k2<<<BB*HH*NC, 256, 0, stream>>>(Xb, Qb, Vb, S, out);
}